// Round 17
// baseline (530.084 us; speedup 1.0000x reference)
//
#include <hip/hip_runtime.h>
#include <hip/hip_bf16.h>

typedef __attribute__((ext_vector_type(4))) float f32x4;
typedef __attribute__((ext_vector_type(8))) short bf16x8;
typedef __attribute__((ext_vector_type(8))) unsigned short u16x8;

static __device__ __forceinline__ ushort f2b(float f) {
  union { float f; unsigned u; } v; v.f = f;
  unsigned r = v.u + 0x7fffu + ((v.u >> 16) & 1u);
  return (ushort)(r >> 16);
}
static __device__ __forceinline__ float b2f(ushort u) {
  union { unsigned u; float f; } v; v.u = ((unsigned)u) << 16; return v.f;
}

static __device__ __forceinline__ float gelu_fast(float g) {
  const float c0 = 0.7978845608028654f, c1 = 0.044715f;
  const float u = c0 * (g + c1 * g * g * g);
  const float e = __expf(2.0f * u);
  const float t = 1.0f - 2.0f / (e + 1.0f);
  return 0.5f * g * (1.0f + t);
}

static __device__ __forceinline__ void gload_lds16(const void* g, void* l) {
  __builtin_amdgcn_global_load_lds(
      (__attribute__((address_space(1))) void*)(g),
      (__attribute__((address_space(3))) void*)(l), 16, 0, 0);
}

#define MFMA_BF16 __builtin_amdgcn_mfma_f32_16x16x32_bf16

// ---------------- merged weight transpose + cast (all 6 weights, 1 launch) ---
struct TCArgs {
  const float* src[6];
  ushort* dst[6];
};

__global__ __launch_bounds__(256) void transpose_cast_all_kernel(TCArgs a) {
  __shared__ float tile[32][33];
  const int t = blockIdx.x;
  int wi, local;
  if (t < 4096)      { wi = t >> 10;  local = t & 1023; }
  else if (t < 8192) { wi = 4;        local = t - 4096; }
  else               { wi = 5;        local = t - 8192; }
  const int K = (wi == 5) ? 2048 : 1024;
  const int N = (wi == 4) ? 4096 : 1024;
  const int nt = N >> 5;
  const int n0 = (local % nt) * 32;
  const int k0 = (local / nt) * 32;
  const float* W = a.src[wi];
  ushort* Wt = a.dst[wi];
  const int tx = threadIdx.x, ty = threadIdx.y;  // 32 x 8
#pragma unroll
  for (int r = 0; r < 32; r += 8)
    tile[ty + r][tx] = W[(size_t)(k0 + ty + r) * N + n0 + tx];
  __syncthreads();
#pragma unroll
  for (int r = 0; r < 32; r += 8)
    Wt[(size_t)(n0 + ty + r) * K + k0 + tx] = f2b(tile[tx][ty + r]);
}

// ---------------- layernorm (rows of 1024) -> bf16; input fp32 or bf16 -------
template <int BF16IN>
__global__ __launch_bounds__(256) void ln_kernel(
    const void* __restrict__ xin, const float* __restrict__ g,
    const float* __restrict__ bb, ushort* __restrict__ out) {
  const int row = blockIdx.x;
  float v0, v1, v2, v3;
  if (BF16IN) {
    const ushort* xr = (const ushort*)xin + (size_t)row * 1024;
    const ushort4 u = *(const ushort4*)&xr[threadIdx.x * 4];
    v0 = b2f(u.x); v1 = b2f(u.y); v2 = b2f(u.z); v3 = b2f(u.w);
  } else {
    const float* xr = (const float*)xin + (size_t)row * 1024;
    const float4 u = *(const float4*)&xr[threadIdx.x * 4];
    v0 = u.x; v1 = u.y; v2 = u.z; v3 = u.w;
  }
  float s = v0 + v1 + v2 + v3;
  float s2 = v0 * v0 + v1 * v1 + v2 * v2 + v3 * v3;
#pragma unroll
  for (int off = 32; off > 0; off >>= 1) {
    s += __shfl_down(s, off);
    s2 += __shfl_down(s2, off);
  }
  __shared__ float red[8];
  const int lane = threadIdx.x & 63, wv = threadIdx.x >> 6;
  if (lane == 0) { red[wv] = s; red[4 + wv] = s2; }
  __syncthreads();
  s = red[0] + red[1] + red[2] + red[3];
  s2 = red[4] + red[5] + red[6] + red[7];
  const float mu = s * (1.0f / 1024.0f);
  const float rs = rsqrtf(s2 * (1.0f / 1024.0f) - mu * mu + 1e-5f);
  const int c = threadIdx.x * 4;
  ushort4 o;
  o.x = f2b((v0 - mu) * rs * g[c + 0] + bb[c + 0]);
  o.y = f2b((v1 - mu) * rs * g[c + 1] + bb[c + 1]);
  o.z = f2b((v2 - mu) * rs * g[c + 2] + bb[c + 2]);
  o.w = f2b((v3 - mu) * rs * g[c + 3] + bb[c + 3]);
  *(ushort4*)&out[(size_t)row * 1024 + c] = o;
}

// ---------------- 256x256 8-phase GEMM: C = A[M,K] * Bt[N,K]^T ---------------
// Round-11 config (best measured): BK=64, dbuf 128KB, K-loop unrolled x2,
// base+immediate ds_read addressing, counted vmcnt(2)/tile, 0 bank conflicts.
// NOTE: 128 acc regs/wave => max 2 waves/SIMD => 1 block/CU (launch_bounds
// (512,2)); (512,4) forces a 128-reg cap and spills the accumulator (r15).
template <int MODE>
__global__ __launch_bounds__(512, 2) void gemm256_kernel(
    const ushort* __restrict__ A, const ushort* __restrict__ Bt,
    const int M, const int N, const int K,
    ushort* __restrict__ Cb, float* __restrict__ Cf,
    const float* __restrict__ bias, const float* __restrict__ resf,
    const ushort* __restrict__ resb) {
  __shared__ __align__(16) ushort lds[2 * 32768];  // 128KB

  const int ntn = N >> 8;
  const int bn = blockIdx.x % ntn;
  const int bm = blockIdx.x / ntn;
  const int tid = threadIdx.x;
  const int l = tid & 63, w = tid >> 6;
  const int wm = w >> 2, wn = w & 3;
  const int fr = l & 15, fq = l >> 4;

  const ushort* Ab = A + (size_t)bm * 256 * K;
  const ushort* Bb = Bt + (size_t)bn * 256 * K;

  const int lr = l >> 3;
  const int sc = (((l & 7) ^ lr) * 8);

  const char* ldsc = (const char*)lds;
  const int fr7 = fr & 7;
  const unsigned s0 = (unsigned)((fq ^ fr7) * 16);
  const unsigned s1 = (unsigned)(((4 + fq) ^ fr7) * 16);
  const unsigned cA0 = (unsigned)((wm * 128 + fr) * 128) + s0;
  const unsigned cA1 = (unsigned)((wm * 128 + fr) * 128) + s1;
  const unsigned cB0 = 32768u + (unsigned)((wn * 64 + fr) * 128) + s0;
  const unsigned cB1 = 32768u + (unsigned)((wn * 64 + fr) * 128) + s1;
  const unsigned dA0 = cA0 + 65536u, dA1 = cA1 + 65536u;
  const unsigned dB0 = cB0 + 65536u, dB1 = cB1 + 65536u;

  f32x4 acc[8][4];
#pragma unroll
  for (int m = 0; m < 8; m++)
#pragma unroll
    for (int n = 0; n < 4; n++) acc[m][n] = (f32x4)0.0f;

  const int NT = K >> 6;

#define STG_A(h, tt, DSTU)                                                     \
  { _Pragma("unroll") for (int i = 0; i < 2; i++) {                            \
      const int rr = (h) * 128 + i * 64 + w * 8;                               \
      gload_lds16(Ab + (size_t)(rr + lr) * K + (size_t)(tt) * 64 + sc,         \
                  &lds[(DSTU) + rr * 64]); } }
#define STG_B(h, tt, DSTU)                                                     \
  { _Pragma("unroll") for (int i = 0; i < 2; i++) {                            \
      const int rr = (h) * 128 + i * 64 + w * 8;                               \
      gload_lds16(Bb + (size_t)(rr + lr) * K + (size_t)(tt) * 64 + sc,         \
                  &lds[(DSTU) + 16384 + rr * 64]); } }

#define GPHASES(tt, bA0v, bA1v, bB0v, bB1v, DSTU, HASNEXT)                     \
  {                                                                            \
    bf16x8 af[4][2], bfv[4][2];                                                \
    if (HASNEXT) {                                                             \
      STG_A(0, (tt) + 1, DSTU);                                                \
      asm volatile("s_waitcnt vmcnt(2)" ::: "memory");                         \
    } else {                                                                   \
      asm volatile("s_waitcnt vmcnt(0)" ::: "memory");                         \
    }                                                                          \
    __builtin_amdgcn_s_barrier();                                              \
    asm volatile("" ::: "memory");                                             \
    _Pragma("unroll") for (int m = 0; m < 4; m++) {                            \
      af[m][0] = *(const bf16x8*)(ldsc + (bA0v) + m * 2048);                   \
      af[m][1] = *(const bf16x8*)(ldsc + (bA1v) + m * 2048);                   \
    }                                                                          \
    _Pragma("unroll") for (int n = 0; n < 2; n++) {                            \
      bfv[n][0] = *(const bf16x8*)(ldsc + (bB0v) + n * 2048);                  \
      bfv[n][1] = *(const bf16x8*)(ldsc + (bB1v) + n * 2048);                  \
    }                                                                          \
    __builtin_amdgcn_s_setprio(1);                                             \
    _Pragma("unroll") for (int m = 0; m < 4; m++)                              \
      _Pragma("unroll") for (int n = 0; n < 2; n++)                            \
        _Pragma("unroll") for (int kk = 0; kk < 2; kk++)                       \
          acc[m][n] = MFMA_BF16(af[m][kk], bfv[n][kk], acc[m][n], 0, 0, 0);    \
    __builtin_amdgcn_s_setprio(0);                                             \
    asm volatile("" ::: "memory");                                             \
    __builtin_amdgcn_s_barrier();                                              \
    if (HASNEXT) STG_A(1, (tt) + 1, DSTU);                                     \
    _Pragma("unroll") for (int n = 2; n < 4; n++) {                            \
      bfv[n][0] = *(const bf16x8*)(ldsc + (bB0v) + n * 2048);                  \
      bfv[n][1] = *(const bf16x8*)(ldsc + (bB1v) + n * 2048);                  \
    }                                                                          \
    __builtin_amdgcn_s_barrier();                                              \
    asm volatile("" ::: "memory");                                             \
    __builtin_amdgcn_s_setprio(1);                                             \
    _Pragma("unroll") for (int m = 0; m < 4; m++)                              \
      _Pragma("unroll") for (int n = 2; n < 4; n++)                            \
        _Pragma("unroll") for (int kk = 0; kk < 2; kk++)                       \
          acc[m][n] = MFMA_BF16(af[m][kk], bfv[n][kk], acc[m][n], 0, 0, 0);    \
    __builtin_amdgcn_s_setprio(0);                                             \
    asm volatile("" ::: "memory");                                             \
    __builtin_amdgcn_s_barrier();                                              \
    if (HASNEXT) STG_B(0, (tt) + 1, DSTU);                                     \
    _Pragma("unroll") for (int m = 0; m < 4; m++) {                            \
      af[m][0] = *(const bf16x8*)(ldsc + (bA0v) + (m + 4) * 2048);             \
      af[m][1] = *(const bf16x8*)(ldsc + (bA1v) + (m + 4) * 2048);             \
    }                                                                          \
    __builtin_amdgcn_s_barrier();                                              \
    asm volatile("" ::: "memory");                                             \
    __builtin_amdgcn_s_setprio(1);                                             \
    _Pragma("unroll") for (int m = 0; m < 4; m++)                              \
      _Pragma("unroll") for (int n = 0; n < 2; n++)                            \
        _Pragma("unroll") for (int kk = 0; kk < 2; kk++)                       \
          acc[m + 4][n] = MFMA_BF16(af[m][kk], bfv[n][kk], acc[m + 4][n], 0, 0, 0); \
    __builtin_amdgcn_s_setprio(0);                                             \
    asm volatile("" ::: "memory");                                             \
    __builtin_amdgcn_s_barrier();                                              \
    if (HASNEXT) STG_B(1, (tt) + 1, DSTU);                                     \
    __builtin_amdgcn_s_barrier();                                              \
    asm volatile("" ::: "memory");                                             \
    __builtin_amdgcn_s_setprio(1);                                             \
    _Pragma("unroll") for (int m = 0; m < 4; m++)                              \
      _Pragma("unroll") for (int n = 2; n < 4; n++)                            \
        _Pragma("unroll") for (int kk = 0; kk < 2; kk++)                       \
          acc[m + 4][n] = MFMA_BF16(af[m][kk], bfv[n][kk], acc[m + 4][n], 0, 0, 0); \
    __builtin_amdgcn_s_setprio(0);                                             \
    asm volatile("" ::: "memory");                                             \
    __builtin_amdgcn_s_barrier();                                              \
  }

  STG_A(0, 0, 0); STG_A(1, 0, 0); STG_B(0, 0, 0); STG_B(1, 0, 0);

  for (int t = 0; t < NT; t += 2) {
    GPHASES(t, cA0, cA1, cB0, cB1, 32768, true);
    GPHASES(t + 1, dA0, dA1, dB0, dB1, 0, (t + 2 < NT));
  }
#undef GPHASES
#undef STG_A
#undef STG_B

  const int rowb = bm * 256 + wm * 128 + fq * 4;
  const int colb = bn * 256 + wn * 64 + fr;
#pragma unroll
  for (int m = 0; m < 8; m++) {
#pragma unroll
    for (int n = 0; n < 4; n++) {
      const int col = colb + n * 16;
#pragma unroll
      for (int j = 0; j < 4; j++) {
        const int row = rowb + m * 16 + j;
        float vv = acc[m][n][j];
        if (MODE == 2) {
          if (col < 1024) vv *= 0.125f;
          Cb[(size_t)row * N + col] = f2b(vv);
        } else if (MODE == 3) {
          Cb[(size_t)row * N + col] =
              f2b(vv + bias[col] + resf[(size_t)row * N + col]);
        } else if (MODE == 4) {
          Cf[(size_t)row * N + col] =
              vv + bias[col] + b2f(resb[(size_t)row * N + col]);
        } else {
          Cb[(size_t)row * N + col] = f2b(vv);
        }
      }
    }
  }
}

// ---------------- GEGLU GEMM, round-11 config ---------------------------------
__global__ __launch_bounds__(512, 2) void gemm_geglu_kernel(
    const ushort* __restrict__ A, const ushort* __restrict__ W1t,
    const float* __restrict__ b1, ushort* __restrict__ U) {
  const int K = 1024;
  __shared__ __align__(16) ushort lds[2 * 32768];  // 128 KB

  const int bn = blockIdx.x & 15;
  const int bm = blockIdx.x >> 4;
  const int tid = threadIdx.x;
  const int l = tid & 63, w = tid >> 6;
  const int wm = w >> 2, wn = w & 3;
  const int fr = l & 15, fq = l >> 4;

  const ushort* Ab = A + (size_t)bm * 256 * K;
  const ushort* Bab = W1t + (size_t)bn * 128 * K;
  const ushort* Bgb = W1t + (size_t)(2048 + bn * 128) * K;

  const int lr = l >> 3;
  const int sc = (((l & 7) ^ lr) * 8);

  const char* ldsc = (const char*)lds;
  const int fr7 = fr & 7;
  const unsigned s0 = (unsigned)((fq ^ fr7) * 16);
  const unsigned s1 = (unsigned)(((4 + fq) ^ fr7) * 16);
  const unsigned cA0 = (unsigned)((wm * 128 + fr) * 128) + s0;
  const unsigned cA1 = (unsigned)((wm * 128 + fr) * 128) + s1;
  const unsigned cBa0 = 32768u + (unsigned)((wn * 32 + fr) * 128) + s0;
  const unsigned cBa1 = 32768u + (unsigned)((wn * 32 + fr) * 128) + s1;
  const unsigned dA0 = cA0 + 65536u, dA1 = cA1 + 65536u;
  const unsigned dBa0 = cBa0 + 65536u, dBa1 = cBa1 + 65536u;

  f32x4 acca[8][2], accg[8][2];
#pragma unroll
  for (int m = 0; m < 8; m++)
#pragma unroll
    for (int n = 0; n < 2; n++) { acca[m][n] = (f32x4)0.0f; accg[m][n] = (f32x4)0.0f; }

  const int NT = K >> 6;  // 16

#define STG_GA(h, tt, DSTU)                                                    \
  { _Pragma("unroll") for (int i = 0; i < 2; i++) {                            \
      const int rr = (h) * 128 + i * 64 + w * 8;                               \
      gload_lds16(Ab + (size_t)(rr + lr) * K + (size_t)(tt) * 64 + sc,         \
                  &lds[(DSTU) + rr * 64]); } }
#define STG_BA(tt, DSTU)                                                       \
  { _Pragma("unroll") for (int i = 0; i < 2; i++) {                            \
      const int rr = i * 64 + w * 8;                                           \
      gload_lds16(Bab + (size_t)(rr + lr) * K + (size_t)(tt) * 64 + sc,        \
                  &lds[(DSTU) + 16384 + rr * 64]); } }
#define STG_BG(tt, DSTU)                                                       \
  { _Pragma("unroll") for (int i = 0; i < 2; i++) {                            \
      const int rr = i * 64 + w * 8;                                           \
      gload_lds16(Bgb + (size_t)(rr + lr) * K + (size_t)(tt) * 64 + sc,        \
                  &lds[(DSTU) + 24576 + rr * 64]); } }

#define GLPHASES(tt, bA0v, bA1v, bBa0v, bBa1v, DSTU, HASNEXT)                  \
  {                                                                            \
    bf16x8 af[4][2], ba[2][2], bg[2][2];                                       \
    if (HASNEXT) {                                                             \
      STG_GA(0, (tt) + 1, DSTU);                                               \
      asm volatile("s_waitcnt vmcnt(2)" ::: "memory");                         \
    } else {                                                                   \
      asm volatile("s_waitcnt vmcnt(0)" ::: "memory");                         \
    }                                                                          \
    __builtin_amdgcn_s_barrier();                                              \
    asm volatile("" ::: "memory");                                             \
    _Pragma("unroll") for (int m = 0; m < 4; m++) {                            \
      af[m][0] = *(const bf16x8*)(ldsc + (bA0v) + m * 2048);                   \
      af[m][1] = *(const bf16x8*)(ldsc + (bA1v) + m * 2048);                   \
    }                                                                          \
    _Pragma("unroll") for (int n = 0; n < 2; n++) {                            \
      ba[n][0] = *(const bf16x8*)(ldsc + (bBa0v) + n * 2048);                  \
      ba[n][1] = *(const bf16x8*)(ldsc + (bBa1v) + n * 2048);                  \
    }                                                                          \
    __builtin_amdgcn_s_setprio(1);                                             \
    _Pragma("unroll") for (int m = 0; m < 4; m++)                              \
      _Pragma("unroll") for (int n = 0; n < 2; n++)                            \
        _Pragma("unroll") for (int kk = 0; kk < 2; kk++)                       \
          acca[m][n] = MFMA_BF16(af[m][kk], ba[n][kk], acca[m][n], 0, 0, 0);   \
    __builtin_amdgcn_s_setprio(0);                                             \
    asm volatile("" ::: "memory");                                             \
    __builtin_amdgcn_s_barrier();                                              \
    if (HASNEXT) STG_GA(1, (tt) + 1, DSTU);                                    \
    _Pragma("unroll") for (int n = 0; n < 2; n++) {                            \
      bg[n][0] = *(const bf16x8*)(ldsc + (bBa0v) + 16384 + n * 2048);          \
      bg[n][1] = *(const bf16x8*)(ldsc + (bBa1v) + 16384 + n * 2048);          \
    }                                                                          \
    __builtin_amdgcn_s_barrier();                                              \
    asm volatile("" ::: "memory");                                             \
    __builtin_amdgcn_s_setprio(1);                                             \
    _Pragma("unroll") for (int m = 0; m < 4; m++)                              \
      _Pragma("unroll") for (int n = 0; n < 2; n++)                            \
        _Pragma("unroll") for (int kk = 0; kk < 2; kk++)                       \
          accg[m][n] = MFMA_BF16(af[m][kk], bg[n][kk], accg[m][n], 0, 0, 0);   \
    __builtin_amdgcn_s_setprio(0);                                             \
    asm volatile("" ::: "memory");                                             \
    __builtin_amdgcn_s_barrier();                                              \
    if (HASNEXT) STG_BA((tt) + 1, DSTU);                                       \
    _Pragma("unroll") for (int m = 0; m < 4; m++) {                            \
      af[m][0] = *(const bf16x8*)(ldsc + (bA0v) + (m + 4) * 2048);             \
      af[m][1] = *(const bf16x8*)(ldsc + (bA1v) + (m + 4) * 2048);             \
    }                                                                          \
    __builtin_amdgcn_s_barrier();                                              \
    asm volatile("" ::: "memory");                                             \
    __builtin_amdgcn_s_setprio(1);                                             \
    _Pragma("unroll") for (int m = 0; m < 4; m++)                              \
      _Pragma("unroll") for (int n = 0; n < 2; n++)                            \
        _Pragma("unroll") for (int kk = 0; kk < 2; kk++)                       \
          acca[m + 4][n] = MFMA_BF16(af[m][kk], ba[n][kk], acca[m + 4][n], 0, 0, 0); \
    __builtin_amdgcn_s_setprio(0);                                             \
    asm volatile("" ::: "memory");                                             \
    __builtin_amdgcn_s_barrier();                                              \
    if (HASNEXT) STG_BG((tt) + 1, DSTU);                                       \
    __builtin_amdgcn_s_barrier();                                              \
    asm volatile("" ::: "memory");                                             \
    __builtin_amdgcn_s_setprio(1);                                             \
    _Pragma("unroll") for (int m = 0; m < 4; m++)                              \
      _Pragma("unroll") for (int n = 0; n < 2; n++)                            \
        _Pragma("unroll") for (int kk = 0; kk < 2; kk++)                       \
          accg[m + 4][n] = MFMA_BF16(af[m][kk], bg[n][kk], accg[m + 4][n], 0, 0, 0); \
    __builtin_amdgcn_s_setprio(0);                                             \
    asm volatile("" ::: "memory");                                             \
    __builtin_amdgcn_s_barrier();                                              \
  }

  STG_GA(0, 0, 0); STG_GA(1, 0, 0); STG_BA(0, 0); STG_BG(0, 0);

  for (int t = 0; t < NT; t += 2) {
    GLPHASES(t, cA0, cA1, cBa0, cBa1, 32768, true);
    GLPHASES(t + 1, dA0, dA1, dBa0, dBa1, 0, (t + 2 < NT));
  }
#undef GLPHASES
#undef STG_GA
#undef STG_BA
#undef STG_BG

  const int rowb = bm * 256 + wm * 128 + fq * 4;
  const int colb = bn * 128 + wn * 32 + fr;
#pragma unroll
  for (int m = 0; m < 8; m++) {
#pragma unroll
    for (int n = 0; n < 2; n++) {
      const int col = colb + n * 16;
      const float b1a = b1[col];
      const float b1g = b1[2048 + col];
#pragma unroll
      for (int j = 0; j < 4; j++) {
        const int row = rowb + m * 16 + j;
        const float a = acca[m][n][j] + b1a;
        const float gg = accg[m][n][j] + b1g;
        U[(size_t)row * 2048 + col] = f2b(a * gelu_fast(gg));
      }
    }
  }
}

// ---------------- windowed causal attention, T14 async-STAGE split -----------
// Per chunk: write prefetched regs->LDS, issue next chunk's global loads
// (in flight across compute), barrier, compute, barrier. +16 VGPR.
__global__ __launch_bounds__(256, 3) void attn_kernel(
    const ushort* __restrict__ Q, const ushort* __restrict__ Kb,
    const ushort* __restrict__ Vb, ushort* __restrict__ O, const int qs) {
  const int bx = blockIdx.x;
  const int n = bx & 15;
  const int h = (bx >> 4) & 15;
  const int b = bx >> 8;
  const int tid = threadIdx.x;
  const int lane = tid & 63, wv = tid >> 6;
  const int fr = lane & 15, fq = lane >> 4;

  __shared__ __align__(16) ushort Kl[64 * 72];
  __shared__ __align__(16) ushort Vt[64 * 70];
  __shared__ __align__(16) ushort Pl[4][64 * 68];

  const size_t qrow0 = (size_t)b * 4096 + (size_t)n * 256;

  bf16x8 qf[4][2];
#pragma unroll
  for (int m = 0; m < 4; m++)
#pragma unroll
    for (int kh = 0; kh < 2; kh++)
      qf[m][kh] = *(const bf16x8*)&Q[(qrow0 + wv * 64 + m * 16 + fr) * qs + h * 64 + kh * 32 + fq * 8];

  f32x4 oacc[4][4];
#pragma unroll
  for (int m = 0; m < 4; m++)
#pragma unroll
    for (int d = 0; d < 4; d++) oacc[m][d] = (f32x4)0.0f;

  float lsum[4][4];
#pragma unroll
  for (int m = 0; m < 4; m++)
#pragma unroll
    for (int j = 0; j < 4; j++) lsum[m][j] = 0.0f;

  const int c0 = (n == 0) ? 4 : 0;
  // staging indices (constant per thread): rows rr0/rr1, col segment cs2
  const int rr0 = tid >> 3, rr1 = (tid + 256) >> 3;
  const int cs2 = tid & 7;
  const size_t kvbase = (size_t)((long long)b * 4096 + (long long)n * 256 - 256);

  u16x8 kreg[2], vreg[2];
  // prefetch chunk c0
  {
    const size_t r0 = kvbase + (size_t)(c0 * 64);
    kreg[0] = *(const u16x8*)&Kb[(r0 + rr0) * qs + h * 64 + cs2 * 8];
    vreg[0] = *(const u16x8*)&Vb[(r0 + rr0) * qs + h * 64 + cs2 * 8];
    kreg[1] = *(const u16x8*)&Kb[(r0 + rr1) * qs + h * 64 + cs2 * 8];
    vreg[1] = *(const u16x8*)&Vb[(r0 + rr1) * qs + h * 64 + cs2 * 8];
  }

  for (int c = c0; c < 8; c++) {
    // write prefetched regs into LDS (LDS free: after prev trailing barrier)
    *(u16x8*)&Kl[rr0 * 72 + cs2 * 8] = kreg[0];
    *(u16x8*)&Kl[rr1 * 72 + cs2 * 8] = kreg[1];
#pragma unroll
    for (int i = 0; i < 8; i++) {
      Vt[(cs2 * 8 + i) * 70 + rr0] = (ushort)vreg[0][i];
      Vt[(cs2 * 8 + i) * 70 + rr1] = (ushort)vreg[1][i];
    }
    // issue next chunk's global loads; they stay in flight across compute
    if (c + 1 < 8) {
      const size_t r1 = kvbase + (size_t)((c + 1) * 64);
      kreg[0] = *(const u16x8*)&Kb[(r1 + rr0) * qs + h * 64 + cs2 * 8];
      vreg[0] = *(const u16x8*)&Vb[(r1 + rr0) * qs + h * 64 + cs2 * 8];
      kreg[1] = *(const u16x8*)&Kb[(r1 + rr1) * qs + h * 64 + cs2 * 8];
      vreg[1] = *(const u16x8*)&Vb[(r1 + rr1) * qs + h * 64 + cs2 * 8];
    }
    __syncthreads();

    if (c <= wv + 4) {
      const bool diag = (c == wv + 4);
#pragma unroll
      for (int nn = 0; nn < 4; nn++) {
        f32x4 sa[4];
#pragma unroll
        for (int m = 0; m < 4; m++) sa[m] = (f32x4)0.0f;
#pragma unroll
        for (int kh = 0; kh < 2; kh++) {
          const bf16x8 bk = *(const bf16x8*)&Kl[(nn * 16 + fr) * 72 + kh * 32 + fq * 8];
#pragma unroll
          for (int m = 0; m < 4; m++)
            sa[m] = MFMA_BF16(qf[m][kh], bk, sa[m], 0, 0, 0);
        }
#pragma unroll
        for (int m = 0; m < 4; m++)
#pragma unroll
          for (int j = 0; j < 4; j++) {
            float p = __expf(sa[m][j]);
            if (diag && (nn * 16 + fr > m * 16 + fq * 4 + j)) p = 0.0f;
            lsum[m][j] += p;
            Pl[wv][(m * 16 + fq * 4 + j) * 68 + nn * 16 + fr] = f2b(p);
          }
      }
      __builtin_amdgcn_s_setprio(1);
#pragma unroll
      for (int kh = 0; kh < 2; kh++) {
        bf16x8 pa[4];
#pragma unroll
        for (int m = 0; m < 4; m++)
          pa[m] = *(const bf16x8*)&Pl[wv][(m * 16 + fr) * 68 + kh * 32 + fq * 8];
#pragma unroll
        for (int d = 0; d < 4; d++) {
          const bf16x8 vb = *(const bf16x8*)&Vt[(d * 16 + fr) * 70 + kh * 32 + fq * 8];
#pragma unroll
          for (int m = 0; m < 4; m++)
            oacc[m][d] = MFMA_BF16(pa[m], vb, oacc[m][d], 0, 0, 0);
        }
      }
      __builtin_amdgcn_s_setprio(0);
    }
    __syncthreads();
  }

  float rl[4][4];
#pragma unroll
  for (int m = 0; m < 4; m++)
#pragma unroll
    for (int j = 0; j < 4; j++) {
      float t = lsum[m][j];
      t += __shfl_xor(t, 1);
      t += __shfl_xor(t, 2);
      t += __shfl_xor(t, 4);
      t += __shfl_xor(t, 8);
      rl[m][j] = 1.0f / t;
    }

#pragma unroll
  for (int m = 0; m < 4; m++)
#pragma unroll
    for (int d = 0; d < 4; d++)
#pragma unroll
      for (int j = 0; j < 4; j++) {
        const float o = oacc[m][d][j] * rl[m][j];
        O[(qrow0 + wv * 64 + m * 16 + fq * 4 + j) * 1024 + h * 64 + d * 16 + fr] = f2b(o);
      }
}

// ---------------- host launcher ----------------------------------------------
extern "C" void kernel_launch(void* const* d_in, const int* in_sizes, int n_in,
                              void* d_out, int out_size, void* d_ws, size_t ws_size,
                              hipStream_t stream) {
  (void)in_sizes; (void)n_in; (void)out_size; (void)ws_size;
  const float* x     = (const float*)d_in[0];
  const float* ln1_g = (const float*)d_in[1];
  const float* ln1_b = (const float*)d_in[2];
  const float* ln2_g = (const float*)d_in[3];
  const float* ln2_b = (const float*)d_in[4];
  const float* Wq    = (const float*)d_in[5];
  const float* Wk    = (const float*)d_in[6];
  const float* Wv    = (const float*)d_in[7];
  const float* Wo    = (const float*)d_in[8];
  const float* bo    = (const float*)d_in[9];
  const float* W1    = (const float*)d_in[10];
  const float* b1    = (const float*)d_in[11];
  const float* W2    = (const float*)d_in[12];
  const float* b2    = (const float*)d_in[13];

  char* ws = (char*)d_ws;
  const size_t MB = 1ull << 20;
  ushort* WQKVT = (ushort*)(ws + 0 * MB);   // [3072,1024]
  ushort* WOT = (ushort*)(ws + 6 * MB);     // [1024,1024]
  ushort* W1T = (ushort*)(ws + 8 * MB);     // [4096,1024]
  ushort* W2T = (ushort*)(ws + 16 * MB);    // [1024,2048]
  ushort* LN1 = (ushort*)(ws + 20 * MB);    // 32MB
  ushort* ATT = LN1;
  ushort* QKV = (ushort*)(ws + 52 * MB);    // [16384,3072] = 96MB
  ushort* LN2 = (ushort*)(ws + 52 * MB);
  ushort* U   = (ushort*)(ws + 84 * MB);    // 64MB (84..148)
  ushort* X1B = (ushort*)(ws + 148 * MB);   // bf16 residual stream, 32MB
  float*  OUT = (float*)d_out;

  TCArgs ta;
  ta.src[0] = Wq; ta.src[1] = Wk; ta.src[2] = Wv; ta.src[3] = Wo;
  ta.src[4] = W1; ta.src[5] = W2;
  ta.dst[0] = WQKVT;
  ta.dst[1] = WQKVT + (size_t)1024 * 1024;
  ta.dst[2] = WQKVT + (size_t)2048 * 1024;
  ta.dst[3] = WOT;
  ta.dst[4] = W1T;
  ta.dst[5] = W2T;
  transpose_cast_all_kernel<<<10240, dim3(32, 8), 0, stream>>>(ta);

  ln_kernel<0><<<16384, 256, 0, stream>>>(x, ln1_g, ln1_b, LN1);

  // fused QKV (Q pre-scaled by 1/8 in epilogue): [16384,3072]
  gemm256_kernel<2><<<64 * 12, 512, 0, stream>>>(LN1, WQKVT, 16384, 3072, 1024,
                                                 QKV, nullptr, nullptr, nullptr, nullptr);

  attn_kernel<<<1024, 256, 0, stream>>>(QKV, QKV + 1024, QKV + 2048, ATT, 3072);

  // x1 (bf16) = x + ATT*Wo^T + bo
  gemm256_kernel<3><<<64 * 4, 512, 0, stream>>>(ATT, WOT, 16384, 1024, 1024,
                                                X1B, nullptr, bo, x, nullptr);

  ln_kernel<1><<<16384, 256, 0, stream>>>(X1B, ln2_g, ln2_b, LN2);

  // U = a * gelu(g)
  gemm_geglu_kernel<<<64 * 16, 512, 0, stream>>>(LN2, W1T, b1, U);

  // out (fp32) = x1 + U*W2^T + b2
  gemm256_kernel<4><<<64 * 4, 512, 0, stream>>>(U, W2T, 16384, 1024, 2048,
                                                nullptr, OUT, b2, nullptr, X1B);
}

// Round 18
// 503.253 us; speedup vs baseline: 1.0533x; 1.0533x over previous
//
#include <hip/hip_runtime.h>
#include <hip/hip_bf16.h>

typedef __attribute__((ext_vector_type(4))) float f32x4;
typedef __attribute__((ext_vector_type(8))) short bf16x8;
typedef __attribute__((ext_vector_type(8))) unsigned short u16x8;

static __device__ __forceinline__ ushort f2b(float f) {
  union { float f; unsigned u; } v; v.f = f;
  unsigned r = v.u + 0x7fffu + ((v.u >> 16) & 1u);
  return (ushort)(r >> 16);
}
static __device__ __forceinline__ float b2f(ushort u) {
  union { unsigned u; float f; } v; v.u = ((unsigned)u) << 16; return v.f;
}

static __device__ __forceinline__ float gelu_fast(float g) {
  const float c0 = 0.7978845608028654f, c1 = 0.044715f;
  const float u = c0 * (g + c1 * g * g * g);
  const float e = __expf(2.0f * u);
  const float t = 1.0f - 2.0f / (e + 1.0f);
  return 0.5f * g * (1.0f + t);
}

static __device__ __forceinline__ void gload_lds16(const void* g, void* l) {
  __builtin_amdgcn_global_load_lds(
      (__attribute__((address_space(1))) void*)(g),
      (__attribute__((address_space(3))) void*)(l), 16, 0, 0);
}

#define MFMA_BF16 __builtin_amdgcn_mfma_f32_16x16x32_bf16

// ---------------- merged weight transpose + cast (all 6 weights, 1 launch) ---
struct TCArgs {
  const float* src[6];
  ushort* dst[6];
};

__global__ __launch_bounds__(256) void transpose_cast_all_kernel(TCArgs a) {
  __shared__ float tile[32][33];
  const int t = blockIdx.x;
  int wi, local;
  if (t < 4096)      { wi = t >> 10;  local = t & 1023; }
  else if (t < 8192) { wi = 4;        local = t - 4096; }
  else               { wi = 5;        local = t - 8192; }
  const int K = (wi == 5) ? 2048 : 1024;
  const int N = (wi == 4) ? 4096 : 1024;
  const int nt = N >> 5;
  const int n0 = (local % nt) * 32;
  const int k0 = (local / nt) * 32;
  const float* W = a.src[wi];
  ushort* Wt = a.dst[wi];
  const int tx = threadIdx.x, ty = threadIdx.y;  // 32 x 8
#pragma unroll
  for (int r = 0; r < 32; r += 8)
    tile[ty + r][tx] = W[(size_t)(k0 + ty + r) * N + n0 + tx];
  __syncthreads();
#pragma unroll
  for (int r = 0; r < 32; r += 8)
    Wt[(size_t)(n0 + ty + r) * K + k0 + tx] = f2b(tile[tx][ty + r]);
}

// ---------------- layernorm (rows of 1024) -> bf16; input fp32 or bf16 -------
template <int BF16IN>
__global__ __launch_bounds__(256) void ln_kernel(
    const void* __restrict__ xin, const float* __restrict__ g,
    const float* __restrict__ bb, ushort* __restrict__ out) {
  const int row = blockIdx.x;
  float v0, v1, v2, v3;
  if (BF16IN) {
    const ushort* xr = (const ushort*)xin + (size_t)row * 1024;
    const ushort4 u = *(const ushort4*)&xr[threadIdx.x * 4];
    v0 = b2f(u.x); v1 = b2f(u.y); v2 = b2f(u.z); v3 = b2f(u.w);
  } else {
    const float* xr = (const float*)xin + (size_t)row * 1024;
    const float4 u = *(const float4*)&xr[threadIdx.x * 4];
    v0 = u.x; v1 = u.y; v2 = u.z; v3 = u.w;
  }
  float s = v0 + v1 + v2 + v3;
  float s2 = v0 * v0 + v1 * v1 + v2 * v2 + v3 * v3;
#pragma unroll
  for (int off = 32; off > 0; off >>= 1) {
    s += __shfl_down(s, off);
    s2 += __shfl_down(s2, off);
  }
  __shared__ float red[8];
  const int lane = threadIdx.x & 63, wv = threadIdx.x >> 6;
  if (lane == 0) { red[wv] = s; red[4 + wv] = s2; }
  __syncthreads();
  s = red[0] + red[1] + red[2] + red[3];
  s2 = red[4] + red[5] + red[6] + red[7];
  const float mu = s * (1.0f / 1024.0f);
  const float rs = rsqrtf(s2 * (1.0f / 1024.0f) - mu * mu + 1e-5f);
  const int c = threadIdx.x * 4;
  ushort4 o;
  o.x = f2b((v0 - mu) * rs * g[c + 0] + bb[c + 0]);
  o.y = f2b((v1 - mu) * rs * g[c + 1] + bb[c + 1]);
  o.z = f2b((v2 - mu) * rs * g[c + 2] + bb[c + 2]);
  o.w = f2b((v3 - mu) * rs * g[c + 3] + bb[c + 3]);
  *(ushort4*)&out[(size_t)row * 1024 + c] = o;
}

// ---------------- 256x256 8-phase GEMM: C = A[M,K] * Bt[N,K]^T ---------------
// Round-11 config (best measured): BK=64, dbuf 128KB, K-loop unrolled x2,
// base+immediate ds_read addressing, counted vmcnt(2)/tile, 0 bank conflicts.
// NOTE: 128 acc regs/wave => max 2 waves/SIMD => 1 block/CU (launch_bounds
// (512,2)); (512,4) forces a 128-reg cap and spills the accumulator (r15).
template <int MODE>
__global__ __launch_bounds__(512, 2) void gemm256_kernel(
    const ushort* __restrict__ A, const ushort* __restrict__ Bt,
    const int M, const int N, const int K,
    ushort* __restrict__ Cb, float* __restrict__ Cf,
    const float* __restrict__ bias, const float* __restrict__ resf,
    const ushort* __restrict__ resb) {
  __shared__ __align__(16) ushort lds[2 * 32768];  // 128KB

  const int ntn = N >> 8;
  const int bn = blockIdx.x % ntn;
  const int bm = blockIdx.x / ntn;
  const int tid = threadIdx.x;
  const int l = tid & 63, w = tid >> 6;
  const int wm = w >> 2, wn = w & 3;
  const int fr = l & 15, fq = l >> 4;

  const ushort* Ab = A + (size_t)bm * 256 * K;
  const ushort* Bb = Bt + (size_t)bn * 256 * K;

  const int lr = l >> 3;
  const int sc = (((l & 7) ^ lr) * 8);

  const char* ldsc = (const char*)lds;
  const int fr7 = fr & 7;
  const unsigned s0 = (unsigned)((fq ^ fr7) * 16);
  const unsigned s1 = (unsigned)(((4 + fq) ^ fr7) * 16);
  const unsigned cA0 = (unsigned)((wm * 128 + fr) * 128) + s0;
  const unsigned cA1 = (unsigned)((wm * 128 + fr) * 128) + s1;
  const unsigned cB0 = 32768u + (unsigned)((wn * 64 + fr) * 128) + s0;
  const unsigned cB1 = 32768u + (unsigned)((wn * 64 + fr) * 128) + s1;
  const unsigned dA0 = cA0 + 65536u, dA1 = cA1 + 65536u;
  const unsigned dB0 = cB0 + 65536u, dB1 = cB1 + 65536u;

  f32x4 acc[8][4];
#pragma unroll
  for (int m = 0; m < 8; m++)
#pragma unroll
    for (int n = 0; n < 4; n++) acc[m][n] = (f32x4)0.0f;

  const int NT = K >> 6;

#define STG_A(h, tt, DSTU)                                                     \
  { _Pragma("unroll") for (int i = 0; i < 2; i++) {                            \
      const int rr = (h) * 128 + i * 64 + w * 8;                               \
      gload_lds16(Ab + (size_t)(rr + lr) * K + (size_t)(tt) * 64 + sc,         \
                  &lds[(DSTU) + rr * 64]); } }
#define STG_B(h, tt, DSTU)                                                     \
  { _Pragma("unroll") for (int i = 0; i < 2; i++) {                            \
      const int rr = (h) * 128 + i * 64 + w * 8;                               \
      gload_lds16(Bb + (size_t)(rr + lr) * K + (size_t)(tt) * 64 + sc,         \
                  &lds[(DSTU) + 16384 + rr * 64]); } }

#define GPHASES(tt, bA0v, bA1v, bB0v, bB1v, DSTU, HASNEXT)                     \
  {                                                                            \
    bf16x8 af[4][2], bfv[4][2];                                                \
    if (HASNEXT) {                                                             \
      STG_A(0, (tt) + 1, DSTU);                                                \
      asm volatile("s_waitcnt vmcnt(2)" ::: "memory");                         \
    } else {                                                                   \
      asm volatile("s_waitcnt vmcnt(0)" ::: "memory");                         \
    }                                                                          \
    __builtin_amdgcn_s_barrier();                                              \
    asm volatile("" ::: "memory");                                             \
    _Pragma("unroll") for (int m = 0; m < 4; m++) {                            \
      af[m][0] = *(const bf16x8*)(ldsc + (bA0v) + m * 2048);                   \
      af[m][1] = *(const bf16x8*)(ldsc + (bA1v) + m * 2048);                   \
    }                                                                          \
    _Pragma("unroll") for (int n = 0; n < 2; n++) {                            \
      bfv[n][0] = *(const bf16x8*)(ldsc + (bB0v) + n * 2048);                  \
      bfv[n][1] = *(const bf16x8*)(ldsc + (bB1v) + n * 2048);                  \
    }                                                                          \
    __builtin_amdgcn_s_setprio(1);                                             \
    _Pragma("unroll") for (int m = 0; m < 4; m++)                              \
      _Pragma("unroll") for (int n = 0; n < 2; n++)                            \
        _Pragma("unroll") for (int kk = 0; kk < 2; kk++)                       \
          acc[m][n] = MFMA_BF16(af[m][kk], bfv[n][kk], acc[m][n], 0, 0, 0);    \
    __builtin_amdgcn_s_setprio(0);                                             \
    asm volatile("" ::: "memory");                                             \
    __builtin_amdgcn_s_barrier();                                              \
    if (HASNEXT) STG_A(1, (tt) + 1, DSTU);                                     \
    _Pragma("unroll") for (int n = 2; n < 4; n++) {                            \
      bfv[n][0] = *(const bf16x8*)(ldsc + (bB0v) + n * 2048);                  \
      bfv[n][1] = *(const bf16x8*)(ldsc + (bB1v) + n * 2048);                  \
    }                                                                          \
    __builtin_amdgcn_s_barrier();                                              \
    asm volatile("" ::: "memory");                                             \
    __builtin_amdgcn_s_setprio(1);                                             \
    _Pragma("unroll") for (int m = 0; m < 4; m++)                              \
      _Pragma("unroll") for (int n = 2; n < 4; n++)                            \
        _Pragma("unroll") for (int kk = 0; kk < 2; kk++)                       \
          acc[m][n] = MFMA_BF16(af[m][kk], bfv[n][kk], acc[m][n], 0, 0, 0);    \
    __builtin_amdgcn_s_setprio(0);                                             \
    asm volatile("" ::: "memory");                                             \
    __builtin_amdgcn_s_barrier();                                              \
    if (HASNEXT) STG_B(0, (tt) + 1, DSTU);                                     \
    _Pragma("unroll") for (int m = 0; m < 4; m++) {                            \
      af[m][0] = *(const bf16x8*)(ldsc + (bA0v) + (m + 4) * 2048);             \
      af[m][1] = *(const bf16x8*)(ldsc + (bA1v) + (m + 4) * 2048);             \
    }                                                                          \
    __builtin_amdgcn_s_barrier();                                              \
    asm volatile("" ::: "memory");                                             \
    __builtin_amdgcn_s_setprio(1);                                             \
    _Pragma("unroll") for (int m = 0; m < 4; m++)                              \
      _Pragma("unroll") for (int n = 0; n < 2; n++)                            \
        _Pragma("unroll") for (int kk = 0; kk < 2; kk++)                       \
          acc[m + 4][n] = MFMA_BF16(af[m][kk], bfv[n][kk], acc[m + 4][n], 0, 0, 0); \
    __builtin_amdgcn_s_setprio(0);                                             \
    asm volatile("" ::: "memory");                                             \
    __builtin_amdgcn_s_barrier();                                              \
    if (HASNEXT) STG_B(1, (tt) + 1, DSTU);                                     \
    __builtin_amdgcn_s_barrier();                                              \
    asm volatile("" ::: "memory");                                             \
    __builtin_amdgcn_s_setprio(1);                                             \
    _Pragma("unroll") for (int m = 0; m < 4; m++)                              \
      _Pragma("unroll") for (int n = 2; n < 4; n++)                            \
        _Pragma("unroll") for (int kk = 0; kk < 2; kk++)                       \
          acc[m + 4][n] = MFMA_BF16(af[m][kk], bfv[n][kk], acc[m + 4][n], 0, 0, 0); \
    __builtin_amdgcn_s_setprio(0);                                             \
    asm volatile("" ::: "memory");                                             \
    __builtin_amdgcn_s_barrier();                                              \
  }

  STG_A(0, 0, 0); STG_A(1, 0, 0); STG_B(0, 0, 0); STG_B(1, 0, 0);

  for (int t = 0; t < NT; t += 2) {
    GPHASES(t, cA0, cA1, cB0, cB1, 32768, true);
    GPHASES(t + 1, dA0, dA1, dB0, dB1, 0, (t + 2 < NT));
  }
#undef GPHASES
#undef STG_A
#undef STG_B

  const int rowb = bm * 256 + wm * 128 + fq * 4;
  const int colb = bn * 256 + wn * 64 + fr;
#pragma unroll
  for (int m = 0; m < 8; m++) {
#pragma unroll
    for (int n = 0; n < 4; n++) {
      const int col = colb + n * 16;
#pragma unroll
      for (int j = 0; j < 4; j++) {
        const int row = rowb + m * 16 + j;
        float vv = acc[m][n][j];
        if (MODE == 2) {
          if (col < 1024) vv *= 0.125f;
          Cb[(size_t)row * N + col] = f2b(vv);
        } else if (MODE == 3) {
          Cb[(size_t)row * N + col] =
              f2b(vv + bias[col] + resf[(size_t)row * N + col]);
        } else if (MODE == 4) {
          Cf[(size_t)row * N + col] =
              vv + bias[col] + b2f(resb[(size_t)row * N + col]);
        } else {
          Cb[(size_t)row * N + col] = f2b(vv);
        }
      }
    }
  }
}

// ---------------- GEGLU GEMM, round-11 config ---------------------------------
__global__ __launch_bounds__(512, 2) void gemm_geglu_kernel(
    const ushort* __restrict__ A, const ushort* __restrict__ W1t,
    const float* __restrict__ b1, ushort* __restrict__ U) {
  const int K = 1024;
  __shared__ __align__(16) ushort lds[2 * 32768];  // 128 KB

  const int bn = blockIdx.x & 15;
  const int bm = blockIdx.x >> 4;
  const int tid = threadIdx.x;
  const int l = tid & 63, w = tid >> 6;
  const int wm = w >> 2, wn = w & 3;
  const int fr = l & 15, fq = l >> 4;

  const ushort* Ab = A + (size_t)bm * 256 * K;
  const ushort* Bab = W1t + (size_t)bn * 128 * K;
  const ushort* Bgb = W1t + (size_t)(2048 + bn * 128) * K;

  const int lr = l >> 3;
  const int sc = (((l & 7) ^ lr) * 8);

  const char* ldsc = (const char*)lds;
  const int fr7 = fr & 7;
  const unsigned s0 = (unsigned)((fq ^ fr7) * 16);
  const unsigned s1 = (unsigned)(((4 + fq) ^ fr7) * 16);
  const unsigned cA0 = (unsigned)((wm * 128 + fr) * 128) + s0;
  const unsigned cA1 = (unsigned)((wm * 128 + fr) * 128) + s1;
  const unsigned cBa0 = 32768u + (unsigned)((wn * 32 + fr) * 128) + s0;
  const unsigned cBa1 = 32768u + (unsigned)((wn * 32 + fr) * 128) + s1;
  const unsigned dA0 = cA0 + 65536u, dA1 = cA1 + 65536u;
  const unsigned dBa0 = cBa0 + 65536u, dBa1 = cBa1 + 65536u;

  f32x4 acca[8][2], accg[8][2];
#pragma unroll
  for (int m = 0; m < 8; m++)
#pragma unroll
    for (int n = 0; n < 2; n++) { acca[m][n] = (f32x4)0.0f; accg[m][n] = (f32x4)0.0f; }

  const int NT = K >> 6;  // 16

#define STG_GA(h, tt, DSTU)                                                    \
  { _Pragma("unroll") for (int i = 0; i < 2; i++) {                            \
      const int rr = (h) * 128 + i * 64 + w * 8;                               \
      gload_lds16(Ab + (size_t)(rr + lr) * K + (size_t)(tt) * 64 + sc,         \
                  &lds[(DSTU) + rr * 64]); } }
#define STG_BA(tt, DSTU)                                                       \
  { _Pragma("unroll") for (int i = 0; i < 2; i++) {                            \
      const int rr = i * 64 + w * 8;                                           \
      gload_lds16(Bab + (size_t)(rr + lr) * K + (size_t)(tt) * 64 + sc,        \
                  &lds[(DSTU) + 16384 + rr * 64]); } }
#define STG_BG(tt, DSTU)                                                       \
  { _Pragma("unroll") for (int i = 0; i < 2; i++) {                            \
      const int rr = i * 64 + w * 8;                                           \
      gload_lds16(Bgb + (size_t)(rr + lr) * K + (size_t)(tt) * 64 + sc,        \
                  &lds[(DSTU) + 24576 + rr * 64]); } }

#define GLPHASES(tt, bA0v, bA1v, bBa0v, bBa1v, DSTU, HASNEXT)                  \
  {                                                                            \
    bf16x8 af[4][2], ba[2][2], bg[2][2];                                       \
    if (HASNEXT) {                                                             \
      STG_GA(0, (tt) + 1, DSTU);                                               \
      asm volatile("s_waitcnt vmcnt(2)" ::: "memory");                         \
    } else {                                                                   \
      asm volatile("s_waitcnt vmcnt(0)" ::: "memory");                         \
    }                                                                          \
    __builtin_amdgcn_s_barrier();                                              \
    asm volatile("" ::: "memory");                                             \
    _Pragma("unroll") for (int m = 0; m < 4; m++) {                            \
      af[m][0] = *(const bf16x8*)(ldsc + (bA0v) + m * 2048);                   \
      af[m][1] = *(const bf16x8*)(ldsc + (bA1v) + m * 2048);                   \
    }                                                                          \
    _Pragma("unroll") for (int n = 0; n < 2; n++) {                            \
      ba[n][0] = *(const bf16x8*)(ldsc + (bBa0v) + n * 2048);                  \
      ba[n][1] = *(const bf16x8*)(ldsc + (bBa1v) + n * 2048);                  \
    }                                                                          \
    __builtin_amdgcn_s_setprio(1);                                             \
    _Pragma("unroll") for (int m = 0; m < 4; m++)                              \
      _Pragma("unroll") for (int n = 0; n < 2; n++)                            \
        _Pragma("unroll") for (int kk = 0; kk < 2; kk++)                       \
          acca[m][n] = MFMA_BF16(af[m][kk], ba[n][kk], acca[m][n], 0, 0, 0);   \
    __builtin_amdgcn_s_setprio(0);                                             \
    asm volatile("" ::: "memory");                                             \
    __builtin_amdgcn_s_barrier();                                              \
    if (HASNEXT) STG_GA(1, (tt) + 1, DSTU);                                    \
    _Pragma("unroll") for (int n = 0; n < 2; n++) {                            \
      bg[n][0] = *(const bf16x8*)(ldsc + (bBa0v) + 16384 + n * 2048);          \
      bg[n][1] = *(const bf16x8*)(ldsc + (bBa1v) + 16384 + n * 2048);          \
    }                                                                          \
    __builtin_amdgcn_s_barrier();                                              \
    asm volatile("" ::: "memory");                                             \
    __builtin_amdgcn_s_setprio(1);                                             \
    _Pragma("unroll") for (int m = 0; m < 4; m++)                              \
      _Pragma("unroll") for (int n = 0; n < 2; n++)                            \
        _Pragma("unroll") for (int kk = 0; kk < 2; kk++)                       \
          accg[m][n] = MFMA_BF16(af[m][kk], bg[n][kk], accg[m][n], 0, 0, 0);   \
    __builtin_amdgcn_s_setprio(0);                                             \
    asm volatile("" ::: "memory");                                             \
    __builtin_amdgcn_s_barrier();                                              \
    if (HASNEXT) STG_BA((tt) + 1, DSTU);                                       \
    _Pragma("unroll") for (int m = 0; m < 4; m++) {                            \
      af[m][0] = *(const bf16x8*)(ldsc + (bA0v) + (m + 4) * 2048);             \
      af[m][1] = *(const bf16x8*)(ldsc + (bA1v) + (m + 4) * 2048);             \
    }                                                                          \
    __builtin_amdgcn_s_barrier();                                              \
    asm volatile("" ::: "memory");                                             \
    __builtin_amdgcn_s_setprio(1);                                             \
    _Pragma("unroll") for (int m = 0; m < 4; m++)                              \
      _Pragma("unroll") for (int n = 0; n < 2; n++)                            \
        _Pragma("unroll") for (int kk = 0; kk < 2; kk++)                       \
          acca[m + 4][n] = MFMA_BF16(af[m][kk], ba[n][kk], acca[m + 4][n], 0, 0, 0); \
    __builtin_amdgcn_s_setprio(0);                                             \
    asm volatile("" ::: "memory");                                             \
    __builtin_amdgcn_s_barrier();                                              \
    if (HASNEXT) STG_BG((tt) + 1, DSTU);                                       \
    __builtin_amdgcn_s_barrier();                                              \
    asm volatile("" ::: "memory");                                             \
    __builtin_amdgcn_s_setprio(1);                                             \
    _Pragma("unroll") for (int m = 0; m < 4; m++)                              \
      _Pragma("unroll") for (int n = 0; n < 2; n++)                            \
        _Pragma("unroll") for (int kk = 0; kk < 2; kk++)                       \
          accg[m + 4][n] = MFMA_BF16(af[m][kk], bg[n][kk], accg[m + 4][n], 0, 0, 0); \
    __builtin_amdgcn_s_setprio(0);                                             \
    asm volatile("" ::: "memory");                                             \
    __builtin_amdgcn_s_barrier();                                              \
  }

  STG_GA(0, 0, 0); STG_GA(1, 0, 0); STG_BA(0, 0); STG_BG(0, 0);

  for (int t = 0; t < NT; t += 2) {
    GLPHASES(t, cA0, cA1, cBa0, cBa1, 32768, true);
    GLPHASES(t + 1, dA0, dA1, dBa0, dBa1, 0, (t + 2 < NT));
  }
#undef GLPHASES
#undef STG_GA
#undef STG_BA
#undef STG_BG

  const int rowb = bm * 256 + wm * 128 + fq * 4;
  const int colb = bn * 128 + wn * 32 + fr;
#pragma unroll
  for (int m = 0; m < 8; m++) {
#pragma unroll
    for (int n = 0; n < 2; n++) {
      const int col = colb + n * 16;
      const float b1a = b1[col];
      const float b1g = b1[2048 + col];
#pragma unroll
      for (int j = 0; j < 4; j++) {
        const int row = rowb + m * 16 + j;
        const float a = acca[m][n][j] + b1a;
        const float gg = accg[m][n][j] + b1g;
        U[(size_t)row * 2048 + col] = f2b(a * gelu_fast(gg));
      }
    }
  }
}

// ---------------- windowed causal attention (no-max online softmax) ----------
__global__ __launch_bounds__(256, 3) void attn_kernel(
    const ushort* __restrict__ Q, const ushort* __restrict__ Kb,
    const ushort* __restrict__ Vb, ushort* __restrict__ O, const int qs) {
  const int bx = blockIdx.x;
  const int n = bx & 15;
  const int h = (bx >> 4) & 15;
  const int b = bx >> 8;
  const int tid = threadIdx.x;
  const int lane = tid & 63, wv = tid >> 6;
  const int fr = lane & 15, fq = lane >> 4;

  __shared__ __align__(16) ushort Kl[64 * 72];
  __shared__ __align__(16) ushort Vt[64 * 70];
  __shared__ __align__(16) ushort Pl[4][64 * 68];

  const size_t qrow0 = (size_t)b * 4096 + (size_t)n * 256;

  bf16x8 qf[4][2];
#pragma unroll
  for (int m = 0; m < 4; m++)
#pragma unroll
    for (int kh = 0; kh < 2; kh++)
      qf[m][kh] = *(const bf16x8*)&Q[(qrow0 + wv * 64 + m * 16 + fr) * qs + h * 64 + kh * 32 + fq * 8];

  f32x4 oacc[4][4];
#pragma unroll
  for (int m = 0; m < 4; m++)
#pragma unroll
    for (int d = 0; d < 4; d++) oacc[m][d] = (f32x4)0.0f;

  float lsum[4][4];
#pragma unroll
  for (int m = 0; m < 4; m++)
#pragma unroll
    for (int j = 0; j < 4; j++) lsum[m][j] = 0.0f;

  const int c0 = (n == 0) ? 4 : 0;
  for (int c = c0; c < 8; c++) {
    const size_t kvrow0 =
        (size_t)((long long)b * 4096 + (long long)n * 256 + (long long)c * 64 - 256);
#pragma unroll
    for (int p = 0; p < 2; p++) {
      const int s = tid + p * 256;
      const int rr = s >> 3, cs2 = s & 7;
      *(u16x8*)&Kl[rr * 72 + cs2 * 8] =
          *(const u16x8*)&Kb[(kvrow0 + rr) * qs + h * 64 + cs2 * 8];
      const u16x8 vvv = *(const u16x8*)&Vb[(kvrow0 + rr) * qs + h * 64 + cs2 * 8];
#pragma unroll
      for (int i = 0; i < 8; i++) Vt[(cs2 * 8 + i) * 70 + rr] = vvv[i];
    }
    __syncthreads();

    if (c <= wv + 4) {
      const bool diag = (c == wv + 4);
#pragma unroll
      for (int nn = 0; nn < 4; nn++) {
        f32x4 sa[4];
#pragma unroll
        for (int m = 0; m < 4; m++) sa[m] = (f32x4)0.0f;
#pragma unroll
        for (int kh = 0; kh < 2; kh++) {
          const bf16x8 bk = *(const bf16x8*)&Kl[(nn * 16 + fr) * 72 + kh * 32 + fq * 8];
#pragma unroll
          for (int m = 0; m < 4; m++)
            sa[m] = MFMA_BF16(qf[m][kh], bk, sa[m], 0, 0, 0);
        }
#pragma unroll
        for (int m = 0; m < 4; m++)
#pragma unroll
          for (int j = 0; j < 4; j++) {
            float p = __expf(sa[m][j]);
            if (diag && (nn * 16 + fr > m * 16 + fq * 4 + j)) p = 0.0f;
            lsum[m][j] += p;
            Pl[wv][(m * 16 + fq * 4 + j) * 68 + nn * 16 + fr] = f2b(p);
          }
      }
      __builtin_amdgcn_s_setprio(1);
#pragma unroll
      for (int kh = 0; kh < 2; kh++) {
        bf16x8 pa[4];
#pragma unroll
        for (int m = 0; m < 4; m++)
          pa[m] = *(const bf16x8*)&Pl[wv][(m * 16 + fr) * 68 + kh * 32 + fq * 8];
#pragma unroll
        for (int d = 0; d < 4; d++) {
          const bf16x8 vb = *(const bf16x8*)&Vt[(d * 16 + fr) * 70 + kh * 32 + fq * 8];
#pragma unroll
          for (int m = 0; m < 4; m++)
            oacc[m][d] = MFMA_BF16(pa[m], vb, oacc[m][d], 0, 0, 0);
        }
      }
      __builtin_amdgcn_s_setprio(0);
    }
    __syncthreads();
  }

  float rl[4][4];
#pragma unroll
  for (int m = 0; m < 4; m++)
#pragma unroll
    for (int j = 0; j < 4; j++) {
      float t = lsum[m][j];
      t += __shfl_xor(t, 1);
      t += __shfl_xor(t, 2);
      t += __shfl_xor(t, 4);
      t += __shfl_xor(t, 8);
      rl[m][j] = 1.0f / t;
    }

#pragma unroll
  for (int m = 0; m < 4; m++)
#pragma unroll
    for (int d = 0; d < 4; d++)
#pragma unroll
      for (int j = 0; j < 4; j++) {
        const float o = oacc[m][d][j] * rl[m][j];
        O[(qrow0 + wv * 64 + m * 16 + fq * 4 + j) * 1024 + h * 64 + d * 16 + fr] = f2b(o);
      }
}

// ---------------- host launcher ----------------------------------------------
extern "C" void kernel_launch(void* const* d_in, const int* in_sizes, int n_in,
                              void* d_out, int out_size, void* d_ws, size_t ws_size,
                              hipStream_t stream) {
  (void)in_sizes; (void)n_in; (void)out_size; (void)ws_size;
  const float* x     = (const float*)d_in[0];
  const float* ln1_g = (const float*)d_in[1];
  const float* ln1_b = (const float*)d_in[2];
  const float* ln2_g = (const float*)d_in[3];
  const float* ln2_b = (const float*)d_in[4];
  const float* Wq    = (const float*)d_in[5];
  const float* Wk    = (const float*)d_in[6];
  const float* Wv    = (const float*)d_in[7];
  const float* Wo    = (const float*)d_in[8];
  const float* bo    = (const float*)d_in[9];
  const float* W1    = (const float*)d_in[10];
  const float* b1    = (const float*)d_in[11];
  const float* W2    = (const float*)d_in[12];
  const float* b2    = (const float*)d_in[13];

  char* ws = (char*)d_ws;
  const size_t MB = 1ull << 20;
  ushort* WQKVT = (ushort*)(ws + 0 * MB);   // [3072,1024]
  ushort* WOT = (ushort*)(ws + 6 * MB);     // [1024,1024]
  ushort* W1T = (ushort*)(ws + 8 * MB);     // [4096,1024]
  ushort* W2T = (ushort*)(ws + 16 * MB);    // [1024,2048]
  ushort* LN1 = (ushort*)(ws + 20 * MB);    // 32MB
  ushort* ATT = LN1;
  ushort* QKV = (ushort*)(ws + 52 * MB);    // [16384,3072] = 96MB
  ushort* LN2 = (ushort*)(ws + 52 * MB);
  ushort* U   = (ushort*)(ws + 84 * MB);    // 64MB (84..148)
  ushort* X1B = (ushort*)(ws + 148 * MB);   // bf16 residual stream, 32MB
  float*  OUT = (float*)d_out;

  TCArgs ta;
  ta.src[0] = Wq; ta.src[1] = Wk; ta.src[2] = Wv; ta.src[3] = Wo;
  ta.src[4] = W1; ta.src[5] = W2;
  ta.dst[0] = WQKVT;
  ta.dst[1] = WQKVT + (size_t)1024 * 1024;
  ta.dst[2] = WQKVT + (size_t)2048 * 1024;
  ta.dst[3] = WOT;
  ta.dst[4] = W1T;
  ta.dst[5] = W2T;
  transpose_cast_all_kernel<<<10240, dim3(32, 8), 0, stream>>>(ta);

  ln_kernel<0><<<16384, 256, 0, stream>>>(x, ln1_g, ln1_b, LN1);

  // fused QKV (Q pre-scaled by 1/8 in epilogue): [16384,3072]
  gemm256_kernel<2><<<64 * 12, 512, 0, stream>>>(LN1, WQKVT, 16384, 3072, 1024,
                                                 QKV, nullptr, nullptr, nullptr, nullptr);

  attn_kernel<<<1024, 256, 0, stream>>>(QKV, QKV + 1024, QKV + 2048, ATT, 3072);

  // x1 (bf16) = x + ATT*Wo^T + bo
  gemm256_kernel<3><<<64 * 4, 512, 0, stream>>>(ATT, WOT, 16384, 1024, 1024,
                                                X1B, nullptr, bo, x, nullptr);

  ln_kernel<1><<<16384, 256, 0, stream>>>(X1B, ln2_g, ln2_b, LN2);

  // U = a * gelu(g)
  gemm_geglu_kernel<<<64 * 16, 512, 0, stream>>>(LN2, W1T, b1, U);

  // out (fp32) = x1 + U*W2^T + b2
  gemm256_kernel<4><<<64 * 4, 512, 0, stream>>>(U, W2T, 16384, 1024, 2048,
                                                nullptr, OUT, b2, nullptr, X1B);
}